// Round 11
// baseline (484.762 us; speedup 1.0000x reference)
//
#include <hip/hip_runtime.h>
#include <hip/hip_bf16.h>

// Fused triplane sample + reshape-semantics MLP (32->128->128->4, ReLU),
// FP32 out, perm [1,2,3,0] baked into w2/b2.
// Channel-group tiling: one 256-thread block = 512 consecutive points x 8
// channels (group g = wg&3) = 8 MFMA tiles. S[8][512] bf16 (8KB) + per-wave
// 16x72 transpose chunks (9KB) = 17.4KB LDS total -> 3+ blocks/CU resident.

#define C_ 32
#define HW_ (128 * 128)
#define HB2 72                /* transpose chunk row stride (shorts), 144B */

typedef short s8v __attribute__((ext_vector_type(8)));
typedef float f4v __attribute__((ext_vector_type(4)));
typedef unsigned int u4v __attribute__((ext_vector_type(4)));

__device__ __attribute__((aligned(64))) unsigned short g_planes[3 * HW_ * C_]; // (3,H,W,C) bf16
__device__ __attribute__((aligned(16))) unsigned short g_w0[128 * 32];
__device__ __attribute__((aligned(16))) unsigned short g_w1[128 * 128];
__device__ __attribute__((aligned(16))) unsigned short g_w2[16 * 128];  // perm-baked, padded
__device__ float g_b0[128];
__device__ float g_b1[128];
__device__ float g_b2p[16];

template <typename TO, typename FROM>
static __device__ __forceinline__ TO bitc(FROM f) {
    union { FROM a; TO b; } u; u.a = f; return u.b;
}

// MFMA operand-type shim (v8i16 vs v8bf16 builtin signature) -- proven.
template <typename V>
static __device__ __forceinline__ auto mfma_k32(V a, V b, f4v c, int)
    -> decltype(__builtin_amdgcn_mfma_f32_16x16x32_bf16(a, b, c, 0, 0, 0)) {
    return __builtin_amdgcn_mfma_f32_16x16x32_bf16(a, b, c, 0, 0, 0);
}
template <typename V>
static __device__ __forceinline__ f4v mfma_k32(V a, V b, f4v c, long) {
    typedef __bf16 b8v __attribute__((ext_vector_type(8)));
    return __builtin_amdgcn_mfma_f32_16x16x32_bf16(bitc<b8v>(a), bitc<b8v>(b), c, 0, 0, 0);
}
static __device__ __forceinline__ f4v MFMA(s8v a, s8v b, f4v c) {
    return mfma_k32(a, b, c, 0);
}

__device__ __forceinline__ unsigned short f2bf(float f) {
    union { float f; unsigned int i; } v; v.f = f;
    unsigned int r = v.i + 0x7FFFu + ((v.i >> 16) & 1u);
    return (unsigned short)(r >> 16);
}

// ---- prep: planes (3C,H,W) fp32 -> (3,H,W,C) bf16 ---------------------------
__global__ void prep_planes_k(const float* __restrict__ tp) {
    int o = blockIdx.x * 256 + threadIdx.x;   // 1572864 threads
    if (o >= 3 * HW_ * C_) return;
    int c  = o & 31;
    int xy = (o >> 5) & (HW_ - 1);
    int pl = o >> 19;
    g_planes[o] = f2bf(tp[(pl * C_ + c) * HW_ + xy]);
}

// ---- prep: weights/biases -> bf16; w2/b2 permuted [1,2,3,0], padded ---------
__global__ void prep_weights_k(const float* __restrict__ w0, const float* __restrict__ b0,
                               const float* __restrict__ w1, const float* __restrict__ b1,
                               const float* __restrict__ w2, const float* __restrict__ b2) {
    int i = blockIdx.x * 256 + threadIdx.x;   // 16384 threads
    if (i < 128 * 32)  g_w0[i] = f2bf(w0[i]);
    if (i < 128 * 128) g_w1[i] = f2bf(w1[i]);
    if (i < 16 * 128) {
        int n = i >> 7, k = i & 127;
        g_w2[i] = f2bf(n < 4 ? w2[((n + 1) & 3) * 128 + k] : 0.0f);
    }
    if (i < 128) { g_b0[i] = b0[i]; g_b1[i] = b1[i]; }
    if (i < 16)  g_b2p[i] = (i < 4) ? b2[(i + 1) & 3] : 0.0f;
}

// ---- bilinear sample: 8 channels (pbase pre-offset by plane & ch-group) -----
__device__ __forceinline__ void sample_plane8(const unsigned short* __restrict__ pbase,
                                              float u, float v, float* facc) {
    float x = (u + 1.0f) * 63.5f;             // align_corners=True, W=H=128
    float y = (v + 1.0f) * 63.5f;
    float xf = floorf(x), yf = floorf(y);
    float wx = x - xf, wy = y - yf;
    int x0 = (int)xf, y0 = (int)yf;
#pragma unroll
    for (int dy = 0; dy < 2; ++dy) {
        int yi = y0 + dy;
        float wyv = dy ? wy : 1.0f - wy;
        bool vy = (yi >= 0) && (yi < 128);
        int yc = yi < 0 ? 0 : (yi > 127 ? 127 : yi);
#pragma unroll
        for (int dx = 0; dx < 2; ++dx) {
            int xi = x0 + dx;
            float wv = (dx ? wx : 1.0f - wx) * wyv;
            bool vx = (xi >= 0) && (xi < 128);
            int xc = xi < 0 ? 0 : (xi > 127 ? 127 : xi);
            wv = (vx && vy) ? wv : 0.0f;
            u4v dw = *(const u4v*)(pbase + (yc * 128 + xc) * C_);
#pragma unroll
            for (int jj = 0; jj < 4; ++jj) {
                facc[2 * jj]     += wv * __uint_as_float(dw[jj] << 16);
                facc[2 * jj + 1] += wv * __uint_as_float(dw[jj] & 0xFFFF0000u);
            }
        }
    }
}

// ---- fused kernel -----------------------------------------------------------
__global__ __launch_bounds__(256) void fused_k(const float* __restrict__ coords,
                                               float* __restrict__ out) {
    // S[8][512] bf16 = 8192 B, then 4 per-wave 16xHB2 chunks (2304 B each).
    __shared__ __attribute__((aligned(16))) unsigned short smem[4096 + 4 * 16 * HB2];
    const int tid  = threadIdx.x;             // 0..255
    const int wave = tid >> 6;                // 0..3
    const int lane = tid & 63;
    const int l15  = lane & 15;
    const int quad = lane >> 4;
    const int ch8  = quad * 8;

    const int wg = blockIdx.x;                // 0..8191
    const int g8 = (wg & 3) * 8;              // channel-group base
    const int nb = (wg >> 2) & 511;           // 512-point block within batch
    const int b  = wg >> 11;                  // batch
    const int n0 = nb << 9;

    // ---- phase A: sample 2 points/thread, 8 channels of this group -> S -----
#pragma unroll
    for (int pt = 0; pt < 2; ++pt) {
        const int nl = tid + pt * 256;        // n_local 0..511
        const float* cp = coords + (size_t)(b * 262144 + n0 + nl) * 3;
        const float gx = cp[0], gy = cp[1], gz = cp[2];
        float facc[8];
#pragma unroll
        for (int c = 0; c < 8; ++c) facc[c] = 0.0f;
        sample_plane8(g_planes + 0 * (HW_ * C_) + g8, gx, gy, facc);  // feat_xy
        sample_plane8(g_planes + 2 * (HW_ * C_) + g8, gx, gz, facc);  // feat_xz
        sample_plane8(g_planes + 1 * (HW_ * C_) + g8, gy, gz, facc);  // feat_yz
#pragma unroll
        for (int c = 0; c < 8; ++c)
            smem[c * 512 + nl] = f2bf(facc[c]);
    }
    __syncthreads();

    // ---- weight fragments ---------------------------------------------------
    s8v w0f[8], w1f[4][8], w2f[4];
#pragma unroll
    for (int nt = 0; nt < 8; ++nt)
        w0f[nt] = *(const s8v*)(g_w0 + (nt * 16 + l15) * 32 + ch8);
#pragma unroll
    for (int kc = 0; kc < 4; ++kc)
#pragma unroll
        for (int nt = 0; nt < 8; ++nt)
            w1f[kc][nt] = *(const s8v*)(g_w1 + (nt * 16 + l15) * 128 + kc * 32 + ch8);
#pragma unroll
    for (int kc = 0; kc < 4; ++kc)
        w2f[kc] = *(const s8v*)(g_w2 + l15 * 128 + kc * 32 + ch8);
    float bias0[8], bias1[8];
#pragma unroll
    for (int nt = 0; nt < 8; ++nt) {
        bias0[nt] = g_b0[nt * 16 + l15];
        bias1[nt] = g_b1[nt * 16 + l15];
    }
    const float bias2 = g_b2p[l15];

    unsigned short* hb = smem + 4096 + wave * (16 * HB2);  // per-wave private
    float* hbf = (float*)hb;

    // ---- phase B: 2 channel-tiles per wave ----------------------------------
#pragma unroll 1
    for (int u = 0; u < 2; ++u) {
        const int cl = wave * 2 + u;          // local channel 0..7
        // A fragment: A[m=l15][k=quad*8+j] = S[cl][l15*32 + ch8 + j]
        const s8v a = *(const s8v*)(smem + cl * 512 + l15 * 32 + ch8);

        // layer 1 in two 64-neuron halves through the chunk buffer
        s8v a2[4];
#pragma unroll
        for (int half = 0; half < 2; ++half) {
#pragma unroll
            for (int ntl = 0; ntl < 4; ++ntl) {
                const int nt = half * 4 + ntl;
                f4v bi;
                bi[0] = bias0[nt]; bi[1] = bias0[nt]; bi[2] = bias0[nt]; bi[3] = bias0[nt];
                f4v c1 = MFMA(a, w0f[nt], bi);
#pragma unroll
                for (int r = 0; r < 4; ++r) {
                    float v = c1[r];
                    hb[(quad * 4 + r) * HB2 + ntl * 16 + l15] = f2bf(v > 0.0f ? v : 0.0f);
                }
            }
            __builtin_amdgcn_s_waitcnt(0);
            a2[half * 2 + 0] = *(const s8v*)(hb + l15 * HB2 + ch8);
            a2[half * 2 + 1] = *(const s8v*)(hb + l15 * HB2 + 32 + ch8);
            __builtin_amdgcn_s_waitcnt(0);    // reads done before next overwrite
        }

        // layer 2 in two 64-neuron halves
        s8v a3[4];
#pragma unroll
        for (int half = 0; half < 2; ++half) {
            f4v d[4];
#pragma unroll
            for (int j = 0; j < 4; ++j) {
                float bv = bias1[half * 4 + j];
                d[j][0] = bv; d[j][1] = bv; d[j][2] = bv; d[j][3] = bv;
            }
#pragma unroll
            for (int kc = 0; kc < 4; ++kc)
#pragma unroll
                for (int j = 0; j < 4; ++j)
                    d[j] = MFMA(a2[kc], w1f[kc][half * 4 + j], d[j]);
#pragma unroll
            for (int j = 0; j < 4; ++j)
#pragma unroll
                for (int r = 0; r < 4; ++r) {
                    float v = d[j][r];
                    hb[(quad * 4 + r) * HB2 + j * 16 + l15] = f2bf(v > 0.0f ? v : 0.0f);
                }
            __builtin_amdgcn_s_waitcnt(0);
            a3[half * 2 + 0] = *(const s8v*)(hb + l15 * HB2 + ch8);
            a3[half * 2 + 1] = *(const s8v*)(hb + l15 * HB2 + 32 + ch8);
            __builtin_amdgcn_s_waitcnt(0);
        }

        // layer 3 -> relu; C layout row=quad*4+r, col=l15 (cols 0..3 valid)
        f4v o;
        o[0] = bias2; o[1] = bias2; o[2] = bias2; o[3] = bias2;
#pragma unroll
        for (int kc = 0; kc < 4; ++kc)
            o = MFMA(a3[kc], w2f[kc], o);

        // transpose 16x4 through LDS -> one coalesced 256B store per tile
        if (l15 < 4) {
#pragma unroll
            for (int r = 0; r < 4; ++r) {
                float v = o[r];
                hbf[(quad * 4 + r) * 4 + l15] = v > 0.0f ? v : 0.0f;
            }
        }
        __builtin_amdgcn_s_waitcnt(0);
        const int t = b * 16384 + (g8 + cl) * 512 + nb;   // global tile index
        if (lane < 16) {
            f4v row = *(const f4v*)(hbf + lane * 4);
            *(f4v*)(out + (size_t)(t * 16 + lane) * 4) = row;
        }
        __builtin_amdgcn_s_waitcnt(0);        // hbf reads done before next tile
    }
}

extern "C" void kernel_launch(void* const* d_in, const int* in_sizes, int n_in,
                              void* d_out, int out_size, void* d_ws, size_t ws_size,
                              hipStream_t stream) {
    const float* coords = (const float*)d_in[0];
    const float* tp = (const float*)d_in[1];
    const float* w0 = (const float*)d_in[2];
    const float* b0 = (const float*)d_in[3];
    const float* w1 = (const float*)d_in[4];
    const float* b1 = (const float*)d_in[5];
    const float* w2 = (const float*)d_in[6];
    const float* b2 = (const float*)d_in[7];
    float* out = (float*)d_out;               // FP32 output

    prep_planes_k<<<6144, 256, 0, stream>>>(tp);
    prep_weights_k<<<64, 256, 0, stream>>>(w0, b0, w1, b1, w2, b2);
    fused_k<<<8192, 256, 0, stream>>>(coords, out);
}

// Round 12
// 420.033 us; speedup vs baseline: 1.1541x; 1.1541x over previous
//
#include <hip/hip_runtime.h>
#include <hip/hip_bf16.h>

// Two-phase: (1) sample_k -- each point sampled once, all 32 channels, written
// to g_samp in (b,channel,n) order, which IS the MLP A-matrix flat layout per
// the reference's reshape(B,N,C) flat-reinterpret. (2) mlp_k -- MFMA MLP
// (32->128->128->4, ReLU), A-tiles read as contiguous 1KB blocks, FP32 out,
// output perm [1,2,3,0] baked into w2/b2.

#define C_ 32
#define HW_ (128 * 128)
#define NPTS (4 * 262144)
#define NTILES (NPTS / 16)
#define HBS 136               /* per-wave transpose buf row stride (bf16) */

typedef short s8v __attribute__((ext_vector_type(8)));
typedef float f4v __attribute__((ext_vector_type(4)));
typedef unsigned int u4v __attribute__((ext_vector_type(4)));

__device__ __attribute__((aligned(64))) unsigned short g_planes[3 * HW_ * C_]; // (3,H,W,C) bf16
__device__ __attribute__((aligned(64))) unsigned short g_samp[NPTS * C_];      // (B,C,N) bf16 = A
__device__ __attribute__((aligned(16))) unsigned short g_w0[128 * 32];
__device__ __attribute__((aligned(16))) unsigned short g_w1[128 * 128];
__device__ __attribute__((aligned(16))) unsigned short g_w2[16 * 128];  // perm-baked, padded
__device__ float g_b0[128];
__device__ float g_b1[128];
__device__ float g_b2p[16];

template <typename TO, typename FROM>
static __device__ __forceinline__ TO bitc(FROM f) {
    union { FROM a; TO b; } u; u.a = f; return u.b;
}

// MFMA operand-type shim (v8i16 vs v8bf16 builtin signature) -- proven.
template <typename V>
static __device__ __forceinline__ auto mfma_k32(V a, V b, f4v c, int)
    -> decltype(__builtin_amdgcn_mfma_f32_16x16x32_bf16(a, b, c, 0, 0, 0)) {
    return __builtin_amdgcn_mfma_f32_16x16x32_bf16(a, b, c, 0, 0, 0);
}
template <typename V>
static __device__ __forceinline__ f4v mfma_k32(V a, V b, f4v c, long) {
    typedef __bf16 b8v __attribute__((ext_vector_type(8)));
    return __builtin_amdgcn_mfma_f32_16x16x32_bf16(bitc<b8v>(a), bitc<b8v>(b), c, 0, 0, 0);
}
static __device__ __forceinline__ f4v MFMA(s8v a, s8v b, f4v c) {
    return mfma_k32(a, b, c, 0);
}

__device__ __forceinline__ unsigned short f2bf(float f) {
    union { float f; unsigned int i; } v; v.f = f;
    unsigned int r = v.i + 0x7FFFu + ((v.i >> 16) & 1u);
    return (unsigned short)(r >> 16);
}

// ---- prep: planes (3C,H,W) fp32 -> (3,H,W,C) bf16 ---------------------------
__global__ void prep_planes_k(const float* __restrict__ tp) {
    int o = blockIdx.x * 256 + threadIdx.x;   // 1572864 threads
    if (o >= 3 * HW_ * C_) return;
    int c  = o & 31;
    int xy = (o >> 5) & (HW_ - 1);
    int pl = o >> 19;
    g_planes[o] = f2bf(tp[(pl * C_ + c) * HW_ + xy]);
}

// ---- prep: weights/biases -> bf16; w2/b2 permuted [1,2,3,0], padded ---------
__global__ void prep_weights_k(const float* __restrict__ w0, const float* __restrict__ b0,
                               const float* __restrict__ w1, const float* __restrict__ b1,
                               const float* __restrict__ w2, const float* __restrict__ b2) {
    int i = blockIdx.x * 256 + threadIdx.x;   // 16384 threads
    if (i < 128 * 32)  g_w0[i] = f2bf(w0[i]);
    if (i < 128 * 128) g_w1[i] = f2bf(w1[i]);
    if (i < 16 * 128) {
        int n = i >> 7, k = i & 127;
        g_w2[i] = f2bf(n < 4 ? w2[((n + 1) & 3) * 128 + k] : 0.0f);
    }
    if (i < 128) { g_b0[i] = b0[i]; g_b1[i] = b1[i]; }
    if (i < 16)  g_b2p[i] = (i < 4) ? b2[(i + 1) & 3] : 0.0f;
}

// ---- bilinear sample: all 32 channels via 16B vector loads ------------------
__device__ __forceinline__ void sample_plane32(const unsigned short* __restrict__ pbase,
                                               float u, float v, float* facc) {
    float x = (u + 1.0f) * 63.5f;             // align_corners=True, W=H=128
    float y = (v + 1.0f) * 63.5f;
    float xf = floorf(x), yf = floorf(y);
    float wx = x - xf, wy = y - yf;
    int x0 = (int)xf, y0 = (int)yf;
#pragma unroll
    for (int dy = 0; dy < 2; ++dy) {
        int yi = y0 + dy;
        float wyv = dy ? wy : 1.0f - wy;
        bool vy = (yi >= 0) && (yi < 128);
        int yc = yi < 0 ? 0 : (yi > 127 ? 127 : yi);
#pragma unroll
        for (int dx = 0; dx < 2; ++dx) {
            int xi = x0 + dx;
            float wv = (dx ? wx : 1.0f - wx) * wyv;
            bool vx = (xi >= 0) && (xi < 128);
            int xc = xi < 0 ? 0 : (xi > 127 ? 127 : xi);
            wv = (vx && vy) ? wv : 0.0f;
            const u4v* cp = (const u4v*)(pbase + (yc * 128 + xc) * C_);
#pragma unroll
            for (int q = 0; q < 4; ++q) {
                u4v dw = cp[q];
#pragma unroll
                for (int jj = 0; jj < 4; ++jj) {
                    facc[q * 8 + 2 * jj]     += wv * __uint_as_float(dw[jj] << 16);
                    facc[q * 8 + 2 * jj + 1] += wv * __uint_as_float(dw[jj] & 0xFFFF0000u);
                }
            }
        }
    }
}

// ---- kernel 1: per-point sampling -> g_samp (b,c,n); no LDS, no barriers ----
__global__ __launch_bounds__(256) void sample_k(const float* __restrict__ coords) {
    const int p = blockIdx.x * 256 + threadIdx.x;   // 0..NPTS-1
    const int b = p >> 18, n = p & 0x3FFFF;
    const float* cp = coords + (size_t)p * 3;
    const float gx = cp[0], gy = cp[1], gz = cp[2];
    float facc[32];
#pragma unroll
    for (int c = 0; c < 32; ++c) facc[c] = 0.0f;
    sample_plane32(g_planes + 0 * (HW_ * C_), gx, gy, facc);  // feat_xy(x,y)
    sample_plane32(g_planes + 2 * (HW_ * C_), gx, gz, facc);  // feat_xz(x,z)
    sample_plane32(g_planes + 1 * (HW_ * C_), gy, gz, facc);  // feat_yz(y,z)
    unsigned short* dst = g_samp + ((size_t)(b * 32) << 18) + n;
#pragma unroll
    for (int c = 0; c < 32; ++c)
        dst[(size_t)c << 18] = f2bf(facc[c]);     // 128B-coalesced per channel
}

// ---- kernel 2: MFMA MLP; A = g_samp flat rows; 4 tiles/wave -----------------
__global__ __launch_bounds__(256) void mlp_k(float* __restrict__ out) {
    __shared__ __attribute__((aligned(16))) unsigned short smem[4 * 16 * HBS]; // 17408B
    const int tid  = threadIdx.x;
    const int wave = tid >> 6;
    const int lane = tid & 63;
    const int l15  = lane & 15;
    const int quad = lane >> 4;
    const int ch8  = quad * 8;

    s8v w0f[8], w1f[4][8], w2f[4];
#pragma unroll
    for (int nt = 0; nt < 8; ++nt)
        w0f[nt] = *(const s8v*)(g_w0 + (nt * 16 + l15) * 32 + ch8);
#pragma unroll
    for (int kc = 0; kc < 4; ++kc)
#pragma unroll
        for (int nt = 0; nt < 8; ++nt)
            w1f[kc][nt] = *(const s8v*)(g_w1 + (nt * 16 + l15) * 128 + kc * 32 + ch8);
#pragma unroll
    for (int kc = 0; kc < 4; ++kc)
        w2f[kc] = *(const s8v*)(g_w2 + l15 * 128 + kc * 32 + ch8);
    float bias0[8], bias1[8];
#pragma unroll
    for (int nt = 0; nt < 8; ++nt) {
        bias0[nt] = g_b0[nt * 16 + l15];
        bias1[nt] = g_b1[nt * 16 + l15];
    }
    const float bias2 = g_b2p[l15];

    unsigned short* hb = smem + wave * (16 * HBS);  // per-wave private
    float* hbf = (float*)hb;
    const int gw = blockIdx.x * 4 + wave;           // 0..16383

#pragma unroll 1
    for (int i = 0; i < 4; ++i) {
        const int t = gw * 4 + i;                   // tile 0..65535
        // A fragment: contiguous 1KB tile, lane reads 16B
        const s8v a = *(const s8v*)(g_samp + (size_t)t * 512 + l15 * 32 + ch8);

        // layer 1: one nt at a time -> hb (C layout), relu
#pragma unroll
        for (int nt = 0; nt < 8; ++nt) {
            f4v bi;
            bi[0] = bias0[nt]; bi[1] = bias0[nt]; bi[2] = bias0[nt]; bi[3] = bias0[nt];
            f4v c1 = MFMA(a, w0f[nt], bi);
#pragma unroll
            for (int r = 0; r < 4; ++r) {
                float v = c1[r];
                hb[(quad * 4 + r) * HBS + nt * 16 + l15] = f2bf(v > 0.0f ? v : 0.0f);
            }
        }
        __builtin_amdgcn_s_waitcnt(0);
        s8v a2[4];
#pragma unroll
        for (int kc = 0; kc < 4; ++kc)
            a2[kc] = *(const s8v*)(hb + l15 * HBS + kc * 32 + ch8);

        // layer 2 in two nt-halves
#pragma unroll
        for (int half = 0; half < 2; ++half) {
            f4v d[4];
#pragma unroll
            for (int j = 0; j < 4; ++j) {
                float bv = bias1[half * 4 + j];
                d[j][0] = bv; d[j][1] = bv; d[j][2] = bv; d[j][3] = bv;
            }
#pragma unroll
            for (int kc = 0; kc < 4; ++kc)
#pragma unroll
                for (int j = 0; j < 4; ++j)
                    d[j] = MFMA(a2[kc], w1f[kc][half * 4 + j], d[j]);
#pragma unroll
            for (int j = 0; j < 4; ++j)
#pragma unroll
                for (int r = 0; r < 4; ++r) {
                    float v = d[j][r];
                    hb[(quad * 4 + r) * HBS + (half * 4 + j) * 16 + l15] =
                        f2bf(v > 0.0f ? v : 0.0f);
                }
        }
        __builtin_amdgcn_s_waitcnt(0);
        s8v a3[4];
#pragma unroll
        for (int kc = 0; kc < 4; ++kc)
            a3[kc] = *(const s8v*)(hb + l15 * HBS + kc * 32 + ch8);

        // layer 3 -> relu; epilogue transpose -> one 256B coalesced store
        f4v o;
        o[0] = bias2; o[1] = bias2; o[2] = bias2; o[3] = bias2;
#pragma unroll
        for (int kc = 0; kc < 4; ++kc)
            o = MFMA(a3[kc], w2f[kc], o);
        __builtin_amdgcn_s_waitcnt(0);        // a3 reads done before hbf reuse
        if (l15 < 4) {
#pragma unroll
            for (int r = 0; r < 4; ++r) {
                float v = o[r];
                hbf[(quad * 4 + r) * 4 + l15] = v > 0.0f ? v : 0.0f;
            }
        }
        __builtin_amdgcn_s_waitcnt(0);
        if (lane < 16) {
            f4v row = *(const f4v*)(hbf + lane * 4);
            *(f4v*)(out + (size_t)(t * 16 + lane) * 4) = row;
        }
        __builtin_amdgcn_s_waitcnt(0);        // hbf reads done before next tile
    }
}

extern "C" void kernel_launch(void* const* d_in, const int* in_sizes, int n_in,
                              void* d_out, int out_size, void* d_ws, size_t ws_size,
                              hipStream_t stream) {
    const float* coords = (const float*)d_in[0];
    const float* tp = (const float*)d_in[1];
    const float* w0 = (const float*)d_in[2];
    const float* b0 = (const float*)d_in[3];
    const float* w1 = (const float*)d_in[4];
    const float* b1 = (const float*)d_in[5];
    const float* w2 = (const float*)d_in[6];
    const float* b2 = (const float*)d_in[7];
    float* out = (float*)d_out;               // FP32 output

    prep_planes_k<<<6144, 256, 0, stream>>>(tp);
    prep_weights_k<<<64, 256, 0, stream>>>(w0, b0, w1, b1, w2, b2);
    sample_k<<<4096, 256, 0, stream>>>(coords);
    mlp_k<<<4096, 256, 0, stream>>>(out);
}